// Round 1
// baseline (5249.713 us; speedup 1.0000x reference)
//
#include <hip/hip_runtime.h>

#define N_NODES 50000
#define N_EDGES 800000
#define D 128
#define N_LAYERS 3
#define OUT_F 16
#define N_GRAPHS 128

// ---------------- scatter: agg[dst] += h[src] over all edges ----------------
// 32 threads per edge, float4 per thread, native fp32 atomics.
__global__ __launch_bounds__(256) void scatter_kernel(
    const float* __restrict__ h, const int* __restrict__ src,
    const int* __restrict__ dst, float* __restrict__ agg) {
  int idx = blockIdx.x * 256 + threadIdx.x;
  int e = idx >> 5;
  int lane = idx & 31;
  if (e >= N_EDGES) return;
  int s = src[e], d = dst[e];
  const float4 v = *(const float4*)&h[(size_t)s * D + lane * 4];
  float* p = &agg[(size_t)d * D + lane * 4];
  unsafeAtomicAdd(p + 0, v.x);
  unsafeAtomicAdd(p + 1, v.y);
  unsafeAtomicAdd(p + 2, v.z);
  unsafeAtomicAdd(p + 3, v.w);
}

// ---- fused per-layer GEMM: out = relu(agg@Wrel + h@Wroot + brel) ----------
// Block: 256 threads = 64 cols (blockIdx.y picks col half) x 4 rowgroups x 8 rows.
// Weights (transposed, XOR-swizzled) staged in LDS: 2 * 64*128 * 4B = 64 KB.
// Row data (agg/h) read via wave-uniform addresses -> scalar loads.
__global__ __launch_bounds__(256) void gemm_layer(
    const float* __restrict__ agg, const float* __restrict__ hv,
    const float* __restrict__ Wrel, const float* __restrict__ Wroot,
    const float* __restrict__ brel, float* __restrict__ out) {
  __shared__ float wts[2][64 * 128];
  const int t = threadIdx.x;
  const int half = blockIdx.y;
  const int c = t & 63;                                   // local col
  const int rg = __builtin_amdgcn_readfirstlane(t >> 6);  // rowgroup (uniform)
  const int cg = half * 64 + c;                           // global col

  // stage swizzled transposed weight half: wts[m][col*128 + swizzle(k)]
  for (int i = 0; i < 32; ++i) {
    int idx = t + i * 256;        // 0..8191
    int k = idx >> 6;             // uniform per wave
    int cl = idx & 63;            // lane
    int swk = (((k >> 2) ^ (cl & 31)) << 2) | (k & 3);
    wts[0][cl * 128 + swk] = Wrel[k * D + half * 64 + cl];
    wts[1][cl * 128 + swk] = Wroot[k * D + half * 64 + cl];
  }
  __syncthreads();

  const float bias = brel[cg];

  for (int tile = blockIdx.x; tile * 32 < N_NODES; tile += gridDim.x) {
    const int row0 = tile * 32 + rg * 8;
    float acc[8];
#pragma unroll
    for (int r = 0; r < 8; ++r) acc[r] = bias;

    if (row0 + 8 <= N_NODES) {
      for (int kc = 0; kc < 32; ++kc) {
        const int off = ((kc ^ (c & 31)) << 2);
        const float4 wr = *(const float4*)&wts[0][c * 128 + off];
        const float4 wo = *(const float4*)&wts[1][c * 128 + off];
#pragma unroll
        for (int r = 0; r < 8; ++r) {
          const float4 a  = *(const float4*)&agg[(size_t)(row0 + r) * D + kc * 4];
          const float4 hh = *(const float4*)&hv[(size_t)(row0 + r) * D + kc * 4];
          acc[r] += a.x * wr.x + a.y * wr.y + a.z * wr.z + a.w * wr.w
                  + hh.x * wo.x + hh.y * wo.y + hh.z * wo.z + hh.w * wo.w;
        }
      }
#pragma unroll
      for (int r = 0; r < 8; ++r)
        out[(size_t)(row0 + r) * D + cg] = fmaxf(acc[r], 0.f);
    } else if (row0 < N_NODES) {
      const int nr = N_NODES - row0;
      for (int kc = 0; kc < 32; ++kc) {
        const int off = ((kc ^ (c & 31)) << 2);
        const float4 wr = *(const float4*)&wts[0][c * 128 + off];
        const float4 wo = *(const float4*)&wts[1][c * 128 + off];
        for (int r = 0; r < nr; ++r) {
          const float4 a  = *(const float4*)&agg[(size_t)(row0 + r) * D + kc * 4];
          const float4 hh = *(const float4*)&hv[(size_t)(row0 + r) * D + kc * 4];
          acc[r] += a.x * wr.x + a.y * wr.y + a.z * wr.z + a.w * wr.w
                  + hh.x * wo.x + hh.y * wo.y + hh.z * wo.z + hh.w * wo.w;
        }
      }
      for (int r = 0; r < nr; ++r)
        out[(size_t)(row0 + r) * D + cg] = fmaxf(acc[r], 0.f);
    }
  }
}

// ---------------- mean-pool (sum part): sums[batch[n]] += h[n] -------------
__global__ __launch_bounds__(256) void pool_kernel(
    const float* __restrict__ h, const int* __restrict__ batch,
    float* __restrict__ sums) {
  int idx = blockIdx.x * 256 + threadIdx.x;
  int n = idx >> 5;
  int lane = idx & 31;
  if (n >= N_NODES) return;
  int g = batch[n];
  const float4 v = *(const float4*)&h[(size_t)n * D + lane * 4];
  float* p = &sums[(size_t)g * D + lane * 4];
  unsafeAtomicAdd(p + 0, v.x);
  unsafeAtomicAdd(p + 1, v.y);
  unsafeAtomicAdd(p + 2, v.z);
  unsafeAtomicAdd(p + 3, v.w);
}

// ---------------- head: out = (pooled @ W1 + b1) @ W2 + b2 ------------------
__device__ __forceinline__ int lb_search(const int* __restrict__ a, int n, int key) {
  int lo = 0, hi = n;
  while (lo < hi) {
    int m = (lo + hi) >> 1;
    if (a[m] < key) lo = m + 1; else hi = m;
  }
  return lo;
}

__global__ __launch_bounds__(128) void head_kernel(
    const float* __restrict__ sums, const int* __restrict__ batch,
    const float* __restrict__ W1, const float* __restrict__ b1,
    const float* __restrict__ W2, const float* __restrict__ b2,
    float* __restrict__ out) {
  __shared__ float pooled[128];
  __shared__ float hidden[128];
  __shared__ float cnt_s;
  const int g = blockIdx.x;
  const int t = threadIdx.x;
  if (t == 0) {
    int lo = lb_search(batch, N_NODES, g);
    int hi = lb_search(batch, N_NODES, g + 1);
    cnt_s = fmaxf((float)(hi - lo), 1.f);
  }
  __syncthreads();
  pooled[t] = sums[(size_t)g * D + t] / cnt_s;
  __syncthreads();
  float acc = b1[t];
  for (int k = 0; k < D; ++k) acc += pooled[k] * W1[k * D + t];
  hidden[t] = acc;
  __syncthreads();
  if (t < OUT_F) {
    float o = b2[t];
    for (int c2 = 0; c2 < D; ++c2) o += hidden[c2] * W2[c2 * OUT_F + t];
    out[(size_t)g * OUT_F + t] = o;
  }
}

extern "C" void kernel_launch(void* const* d_in, const int* in_sizes, int n_in,
                              void* d_out, int out_size, void* d_ws, size_t ws_size,
                              hipStream_t stream) {
  const float* x     = (const float*)d_in[0];
  const int*   ei    = (const int*)d_in[1];   // [2][E]
  const int*   batch = (const int*)d_in[2];   // [N], sorted
  const float* Wrel  = (const float*)d_in[3]; // [3][D][D]
  const float* brel  = (const float*)d_in[4]; // [3][D]
  const float* Wroot = (const float*)d_in[5]; // [3][D][D]
  const float* W1    = (const float*)d_in[6]; // [D][D]
  const float* b1    = (const float*)d_in[7]; // [D]
  const float* W2    = (const float*)d_in[8]; // [D][OUT]
  const float* b2    = (const float*)d_in[9]; // [OUT]
  float* out = (float*)d_out;

  float* agg  = (float*)d_ws;                         // N*D
  float* hA   = agg + (size_t)N_NODES * D;            // N*D
  float* hB   = hA + (size_t)N_NODES * D;             // N*D
  float* sums = hB + (size_t)N_NODES * D;             // G*D

  hipMemsetAsync(sums, 0, (size_t)N_GRAPHS * D * sizeof(float), stream);

  const float* hprev = x;
  float* bufs[2] = {hA, hB};
  for (int l = 0; l < N_LAYERS; ++l) {
    hipMemsetAsync(agg, 0, (size_t)N_NODES * D * sizeof(float), stream);
    scatter_kernel<<<(N_EDGES * 32) / 256, 256, 0, stream>>>(
        hprev, ei, ei + N_EDGES, agg);
    float* hnext = bufs[l & 1];
    gemm_layer<<<dim3(512, 2), 256, 0, stream>>>(
        agg, hprev, Wrel + (size_t)l * D * D, Wroot + (size_t)l * D * D,
        brel + (size_t)l * D, hnext);
    hprev = hnext;
  }

  pool_kernel<<<(N_NODES * 32 + 255) / 256, 256, 0, stream>>>(hprev, batch, sums);
  head_kernel<<<N_GRAPHS, 128, 0, stream>>>(sums, batch, W1, b1, W2, b2, out);
}

// Round 2
// 594.242 us; speedup vs baseline: 8.8343x; 8.8343x over previous
//
#include <hip/hip_runtime.h>

#define N_NODES 50000
#define N_EDGES 800000
#define D 128
#define N_LAYERS 3
#define OUT_F 16
#define N_GRAPHS 128
#define SCAN_B 256
#define N_SCAN_BLOCKS ((N_NODES + SCAN_B - 1) / SCAN_B)  // 196

// ======================= CSR build (counting sort by dst) ===================
__global__ __launch_bounds__(256) void hist_kernel(
    const int* __restrict__ dst, int* __restrict__ cnt) {
  int e = blockIdx.x * 256 + threadIdx.x;
  if (e < N_EDGES) atomicAdd(&cnt[dst[e]], 1);
}

__global__ __launch_bounds__(SCAN_B) void scan1_kernel(
    const int* __restrict__ cnt, int* __restrict__ rowptr, int* __restrict__ bsum) {
  __shared__ int s[SCAN_B];
  int t = threadIdx.x;
  int i = blockIdx.x * SCAN_B + t;
  int v = (i < N_NODES) ? cnt[i] : 0;
  s[t] = v;
  __syncthreads();
  for (int off = 1; off < SCAN_B; off <<= 1) {
    int x = (t >= off) ? s[t - off] : 0;
    __syncthreads();
    s[t] += x;
    __syncthreads();
  }
  if (i < N_NODES) rowptr[i] = s[t] - v;  // exclusive within block
  if (t == SCAN_B - 1) bsum[blockIdx.x] = s[t];
}

__global__ __launch_bounds__(SCAN_B) void scan2_kernel(int* __restrict__ bsum) {
  __shared__ int s[SCAN_B];
  int t = threadIdx.x;
  int v = (t < N_SCAN_BLOCKS) ? bsum[t] : 0;
  s[t] = v;
  __syncthreads();
  for (int off = 1; off < SCAN_B; off <<= 1) {
    int x = (t >= off) ? s[t - off] : 0;
    __syncthreads();
    s[t] += x;
    __syncthreads();
  }
  if (t < N_SCAN_BLOCKS) bsum[t] = s[t] - v;  // exclusive
}

__global__ __launch_bounds__(SCAN_B) void scan3_kernel(
    int* __restrict__ rowptr, const int* __restrict__ bsum, int* __restrict__ wpos) {
  int i = blockIdx.x * SCAN_B + threadIdx.x;
  if (i < N_NODES) {
    int r = rowptr[i] + bsum[i >> 8];
    rowptr[i] = r;
    wpos[i] = r;
  }
  if (i == N_NODES) rowptr[N_NODES] = N_EDGES;
}

__global__ __launch_bounds__(256) void fill_kernel(
    const int* __restrict__ src, const int* __restrict__ dst,
    int* __restrict__ wpos, int* __restrict__ esrc) {
  int e = blockIdx.x * 256 + threadIdx.x;
  if (e >= N_EDGES) return;
  int p = atomicAdd(&wpos[dst[e]], 1);
  esrc[p] = src[e];
}

// ================= aggregate by gather: agg[n] = sum h[esrc[...]] ===========
// 32 lanes per node (float4 per lane covers D=128), no atomics.
__global__ __launch_bounds__(256) void agg_kernel(
    const float* __restrict__ h, const int* __restrict__ rowptr,
    const int* __restrict__ esrc, float* __restrict__ agg) {
  int idx = blockIdx.x * 256 + threadIdx.x;
  int n = idx >> 5;
  int lane = idx & 31;
  if (n >= N_NODES) return;
  int beg = rowptr[n], end = rowptr[n + 1];
  float ax = 0.f, ay = 0.f, az = 0.f, aw = 0.f;
  for (int e = beg; e < end; ++e) {
    int s = esrc[e];
    const float4 v = *(const float4*)&h[(size_t)s * D + lane * 4];
    ax += v.x; ay += v.y; az += v.z; aw += v.w;
  }
  float4 o = {ax, ay, az, aw};
  *(float4*)&agg[(size_t)n * D + lane * 4] = o;
}

// ===== fused GEMM: out = relu(agg@Wrel + h@Wroot + b), in-place out==agg ====
// Block: 256 thr, C-tile 64 rows x 128 cols, micro-tile 4 rows x (4+4) cols.
// LDS: A-tile 64x128 (pad 130, conflict-free) reused for agg then h; W chunk 32x128.
__global__ __launch_bounds__(256) void gemm_layer(
    const float* agg, const float* __restrict__ hv,
    const float* __restrict__ Wrel, const float* __restrict__ Wroot,
    const float* __restrict__ brel, float* outp) {
  __shared__ float At[64 * 130];   // 33,280 B
  __shared__ float Wt[32 * 128];   // 16,384 B
  const int t = threadIdx.x;
  const int tc = t & 15;           // col group: cols tc*4..+3 and 64+tc*4..+3
  const int tr = t >> 4;           // row group: rows tr*4..+3
  const int row0 = blockIdx.x * 64;

  float acc[4][8];
#pragma unroll
  for (int i = 0; i < 4; ++i)
#pragma unroll
    for (int j = 0; j < 8; ++j) acc[i][j] = 0.f;

  for (int mat = 0; mat < 2; ++mat) {
    const float* A = mat ? hv : agg;
    const float* W = mat ? Wroot : Wrel;
    __syncthreads();  // previous At users done
    // stage A tile: 64 rows x 128 floats
#pragma unroll
    for (int j = 0; j < 8; ++j) {
      int idx = t + j * 256;        // 0..2047 float4 units
      int r = idx >> 5, f = idx & 31;
      int gr = row0 + r;
      if (gr >= N_NODES) gr = N_NODES - 1;
      *(float4*)&At[r * 130 + f * 4] = *(const float4*)&A[(size_t)gr * D + f * 4];
    }
    for (int c = 0; c < 4; ++c) {
      __syncthreads();  // previous Wt users / At ready
#pragma unroll
      for (int j = 0; j < 4; ++j) {
        int idx = t + j * 256;      // 0..1023 float4 units over 32x128
        int kk = idx >> 5, f = idx & 31;
        *(float4*)&Wt[kk * 128 + f * 4] =
            *(const float4*)&W[(size_t)(c * 32 + kk) * D + f * 4];
      }
      __syncthreads();
#pragma unroll 4
      for (int kk = 0; kk < 32; ++kk) {
        float a[4];
#pragma unroll
        for (int i = 0; i < 4; ++i) a[i] = At[(tr * 4 + i) * 130 + c * 32 + kk];
        const float4 w0 = *(const float4*)&Wt[kk * 128 + tc * 4];
        const float4 w1 = *(const float4*)&Wt[kk * 128 + 64 + tc * 4];
#pragma unroll
        for (int i = 0; i < 4; ++i) {
          acc[i][0] += a[i] * w0.x; acc[i][1] += a[i] * w0.y;
          acc[i][2] += a[i] * w0.z; acc[i][3] += a[i] * w0.w;
          acc[i][4] += a[i] * w1.x; acc[i][5] += a[i] * w1.y;
          acc[i][6] += a[i] * w1.z; acc[i][7] += a[i] * w1.w;
        }
      }
    }
  }
  // epilogue: bias + relu + store (rows of this block only -> in-place safe)
  const float4 b_lo = *(const float4*)&brel[tc * 4];
  const float4 b_hi = *(const float4*)&brel[64 + tc * 4];
#pragma unroll
  for (int i = 0; i < 4; ++i) {
    int gr = row0 + tr * 4 + i;
    if (gr >= N_NODES) continue;
    float4 o0 = {fmaxf(acc[i][0] + b_lo.x, 0.f), fmaxf(acc[i][1] + b_lo.y, 0.f),
                 fmaxf(acc[i][2] + b_lo.z, 0.f), fmaxf(acc[i][3] + b_lo.w, 0.f)};
    float4 o1 = {fmaxf(acc[i][4] + b_hi.x, 0.f), fmaxf(acc[i][5] + b_hi.y, 0.f),
                 fmaxf(acc[i][6] + b_hi.z, 0.f), fmaxf(acc[i][7] + b_hi.w, 0.f)};
    *(float4*)&outp[(size_t)gr * D + tc * 4] = o0;
    *(float4*)&outp[(size_t)gr * D + 64 + tc * 4] = o1;
  }
}

// ============= pool (segment ranges; batch sorted) + MLP head ===============
__device__ __forceinline__ int lb_search(const int* __restrict__ a, int n, int key) {
  int lo = 0, hi = n;
  while (lo < hi) {
    int m = (lo + hi) >> 1;
    if (a[m] < key) lo = m + 1; else hi = m;
  }
  return lo;
}

__global__ __launch_bounds__(256) void pool_head_kernel(
    const float* __restrict__ h, const int* __restrict__ batch,
    const float* __restrict__ W1, const float* __restrict__ b1,
    const float* __restrict__ W2, const float* __restrict__ b2,
    float* __restrict__ out) {
  __shared__ float part[256];
  __shared__ float pooled[128];
  __shared__ float hidden[128];
  __shared__ int range[2];
  const int g = blockIdx.x;
  const int t = threadIdx.x;
  if (t < 2) range[t] = lb_search(batch, N_NODES, g + t);
  __syncthreads();
  const int lo = range[0], hi = range[1];
  const int col = t & 127, half = t >> 7;
  float s = 0.f;
  for (int n = lo + half; n < hi; n += 2) s += h[(size_t)n * D + col];
  part[t] = s;
  __syncthreads();
  if (t < 128) pooled[t] = (part[t] + part[t + 128]) / fmaxf((float)(hi - lo), 1.f);
  __syncthreads();
  if (t < 128) {
    float a = b1[t];
    for (int k = 0; k < D; ++k) a += pooled[k] * W1[k * D + t];
    hidden[t] = a;
  }
  __syncthreads();
  if (t < OUT_F) {
    float o = b2[t];
    for (int k = 0; k < D; ++k) o += hidden[k] * W2[k * OUT_F + t];
    out[(size_t)g * OUT_F + t] = o;
  }
}

// ============================== launch ======================================
extern "C" void kernel_launch(void* const* d_in, const int* in_sizes, int n_in,
                              void* d_out, int out_size, void* d_ws, size_t ws_size,
                              hipStream_t stream) {
  const float* x     = (const float*)d_in[0];
  const int*   ei    = (const int*)d_in[1];   // [2][E] (src row, dst row)
  const int*   batch = (const int*)d_in[2];   // [N], sorted
  const float* Wrel  = (const float*)d_in[3];
  const float* brel  = (const float*)d_in[4];
  const float* Wroot = (const float*)d_in[5];
  const float* W1    = (const float*)d_in[6];
  const float* b1    = (const float*)d_in[7];
  const float* W2    = (const float*)d_in[8];
  const float* b2    = (const float*)d_in[9];
  float* out = (float*)d_out;

  float* bufA  = (float*)d_ws;                      // N*D floats
  float* bufB  = bufA + (size_t)N_NODES * D;        // N*D floats
  int*   rowptr = (int*)(bufB + (size_t)N_NODES * D);  // N+1
  int*   wpos   = rowptr + (N_NODES + 1);           // N
  int*   esrc   = wpos + N_NODES;                   // E
  int*   bsum   = esrc + N_EDGES;                   // N_SCAN_BLOCKS

  const int* esrc_in = ei;
  const int* edst_in = ei + N_EDGES;

  // ---- CSR build (once per call; ws is re-poisoned every launch) ----
  hipMemsetAsync(wpos, 0, N_NODES * sizeof(int), stream);
  hist_kernel<<<(N_EDGES + 255) / 256, 256, 0, stream>>>(edst_in, wpos);
  scan1_kernel<<<N_SCAN_BLOCKS, SCAN_B, 0, stream>>>(wpos, rowptr, bsum);
  scan2_kernel<<<1, SCAN_B, 0, stream>>>(bsum);
  scan3_kernel<<<N_SCAN_BLOCKS + 1, SCAN_B, 0, stream>>>(rowptr, bsum, wpos);
  fill_kernel<<<(N_EDGES + 255) / 256, 256, 0, stream>>>(esrc_in, edst_in, wpos, esrc);

  // ---- 3 GraphConv layers (gather-agg + in-place fused GEMM) ----
  const float* hprev = x;
  float* aggbuf = bufA;
  float* other  = bufB;
  for (int l = 0; l < N_LAYERS; ++l) {
    agg_kernel<<<(N_NODES * 32 + 255) / 256, 256, 0, stream>>>(
        hprev, rowptr, esrc, aggbuf);
    gemm_layer<<<(N_NODES + 63) / 64, 256, 0, stream>>>(
        aggbuf, hprev, Wrel + (size_t)l * D * D, Wroot + (size_t)l * D * D,
        brel + (size_t)l * D, aggbuf);
    hprev = aggbuf;
    float* tmp = aggbuf; aggbuf = other; other = tmp;
    if (l == 0) aggbuf = bufB, other = bufA;  // explicit: h1=bufA, next agg=bufB
  }

  pool_head_kernel<<<N_GRAPHS, 256, 0, stream>>>(
      hprev, batch, W1, b1, W2, b2, out);
}

// Round 3
// 517.765 us; speedup vs baseline: 10.1392x; 1.1477x over previous
//
#include <hip/hip_runtime.h>

#define N_NODES 50000
#define N_EDGES 800000
#define D 128
#define N_LAYERS 3
#define OUT_F 16
#define N_GRAPHS 128
#define SCAN_B 256
#define N_SCAN_BLOCKS ((N_NODES + SCAN_B - 1) / SCAN_B)  // 196

typedef __attribute__((ext_vector_type(8))) short short8;
typedef __attribute__((ext_vector_type(4))) float floatx4;

__device__ __forceinline__ unsigned short f2bf(float f) {
  unsigned int u = __float_as_uint(f);
  u += 0x7fff + ((u >> 16) & 1);   // RNE
  return (unsigned short)(u >> 16);
}
__device__ __forceinline__ float bf2f(unsigned short b) {
  return __uint_as_float(((unsigned int)b) << 16);
}

// ======================= CSR build (counting sort by dst) ===================
__global__ __launch_bounds__(256) void hist_kernel(
    const int* __restrict__ dst, int* __restrict__ cnt) {
  int e = blockIdx.x * 256 + threadIdx.x;
  if (e < N_EDGES) atomicAdd(&cnt[dst[e]], 1);
}

__global__ __launch_bounds__(SCAN_B) void scan1_kernel(
    const int* __restrict__ cnt, int* __restrict__ rowptr, int* __restrict__ bsum) {
  __shared__ int s[SCAN_B];
  int t = threadIdx.x;
  int i = blockIdx.x * SCAN_B + t;
  int v = (i < N_NODES) ? cnt[i] : 0;
  s[t] = v;
  __syncthreads();
  for (int off = 1; off < SCAN_B; off <<= 1) {
    int x = (t >= off) ? s[t - off] : 0;
    __syncthreads();
    s[t] += x;
    __syncthreads();
  }
  if (i < N_NODES) rowptr[i] = s[t] - v;
  if (t == SCAN_B - 1) bsum[blockIdx.x] = s[t];
}

__global__ __launch_bounds__(SCAN_B) void scan2_kernel(int* __restrict__ bsum) {
  __shared__ int s[SCAN_B];
  int t = threadIdx.x;
  int v = (t < N_SCAN_BLOCKS) ? bsum[t] : 0;
  s[t] = v;
  __syncthreads();
  for (int off = 1; off < SCAN_B; off <<= 1) {
    int x = (t >= off) ? s[t - off] : 0;
    __syncthreads();
    s[t] += x;
    __syncthreads();
  }
  if (t < N_SCAN_BLOCKS) bsum[t] = s[t] - v;
}

__global__ __launch_bounds__(SCAN_B) void scan3_kernel(
    int* __restrict__ rowptr, const int* __restrict__ bsum, int* __restrict__ wpos) {
  int i = blockIdx.x * SCAN_B + threadIdx.x;
  if (i < N_NODES) {
    int r = rowptr[i] + bsum[i >> 8];
    rowptr[i] = r;
    wpos[i] = r;
  }
  if (i == N_NODES) rowptr[N_NODES] = N_EDGES;
}

__global__ __launch_bounds__(256) void fill_kernel(
    const int* __restrict__ src, const int* __restrict__ dst,
    int* __restrict__ wpos, int* __restrict__ esrc) {
  int e = blockIdx.x * 256 + threadIdx.x;
  if (e >= N_EDGES) return;
  int p = atomicAdd(&wpos[dst[e]], 1);
  esrc[p] = src[e];
}

// ================= prep: cast x -> bf16; weights -> transposed hi/lo bf16 ===
__global__ __launch_bounds__(256) void cast_x_kernel(
    const float* __restrict__ x, unsigned short* __restrict__ x16) {
  int i = blockIdx.x * 256 + threadIdx.x;          // handles 4 floats
  if ((size_t)i * 4 >= (size_t)N_NODES * D) return;
  const float4 v = *(const float4*)&x[(size_t)i * 4];
  uint2 o;
  o.x = f2bf(v.x) | ((unsigned)f2bf(v.y) << 16);
  o.y = f2bf(v.z) | ((unsigned)f2bf(v.w) << 16);
  *(uint2*)&x16[(size_t)i * 4] = o;
}

// wt layout per layer: [seg:4][n:128][k:128], segs = {rel_hi, rel_lo, root_hi, root_lo}
__global__ __launch_bounds__(256) void prep_w_kernel(
    const float* __restrict__ Wrel, const float* __restrict__ Wroot,
    unsigned short* __restrict__ wt) {
  int idx = blockIdx.x * 256 + threadIdx.x;   // [l][mat][k][n], n innermost (coalesced read)
  if (idx >= N_LAYERS * 2 * D * D) return;
  int n = idx & 127;
  int k = (idx >> 7) & 127;
  int mat = (idx >> 14) & 1;
  int l = idx >> 15;
  const float* W = mat ? Wroot : Wrel;
  float w = W[(size_t)l * D * D + k * D + n];
  unsigned short hi = f2bf(w);
  unsigned short lo = f2bf(w - bf2f(hi));
  size_t base = (size_t)l * 4 * D * D + (size_t)mat * 2 * D * D;
  wt[base + (size_t)n * D + k] = hi;
  wt[base + D * D + (size_t)n * D + k] = lo;
}

// ============ aggregate by gather (bf16 in, fp32 acc, bf16 out) =============
// 16 lanes per node, 16B loads; no atomics.
__global__ __launch_bounds__(256) void agg16_kernel(
    const unsigned short* __restrict__ h16, const int* __restrict__ rowptr,
    const int* __restrict__ esrc, unsigned short* __restrict__ agg) {
  int idx = blockIdx.x * 256 + threadIdx.x;
  int n = idx >> 4;
  int lane = idx & 15;
  if (n >= N_NODES) return;
  int beg = rowptr[n], end = rowptr[n + 1];
  float a0 = 0, a1 = 0, a2 = 0, a3 = 0, a4 = 0, a5 = 0, a6 = 0, a7 = 0;
  for (int e = beg; e < end; ++e) {
    int s = esrc[e];
    const uint4 v = *(const uint4*)&h16[(size_t)s * D + lane * 8];
    a0 += __uint_as_float(v.x << 16); a1 += __uint_as_float(v.x & 0xffff0000u);
    a2 += __uint_as_float(v.y << 16); a3 += __uint_as_float(v.y & 0xffff0000u);
    a4 += __uint_as_float(v.z << 16); a5 += __uint_as_float(v.z & 0xffff0000u);
    a6 += __uint_as_float(v.w << 16); a7 += __uint_as_float(v.w & 0xffff0000u);
  }
  uint4 o;
  o.x = f2bf(a0) | ((unsigned)f2bf(a1) << 16);
  o.y = f2bf(a2) | ((unsigned)f2bf(a3) << 16);
  o.z = f2bf(a4) | ((unsigned)f2bf(a5) << 16);
  o.w = f2bf(a6) | ((unsigned)f2bf(a7) << 16);
  *(uint4*)&agg[(size_t)n * D + lane * 8] = o;
}

// ====== MFMA GEMM: out = relu([agg|h] @ [Wrel_hi;Wrel_lo;Wroot_hi;Wroot_lo] + b)
// Block 256 = 4 waves; wave w -> rows blockIdx*64 + w*16; 8 col-tiles of 16.
__global__ __launch_bounds__(256) void gemm16_kernel(
    const unsigned short* __restrict__ agg, const unsigned short* __restrict__ hv,
    const unsigned short* __restrict__ wt, const float* __restrict__ brel,
    unsigned short* outp) {
  const int t = threadIdx.x;
  const int wave = t >> 6, lane = t & 63;
  const int m = lane & 15, quad = lane >> 4;
  const int r0 = blockIdx.x * 64 + wave * 16;
  int arow = r0 + m;
  if (arow >= N_NODES) arow = N_NODES - 1;

  floatx4 acc[8];
#pragma unroll
  for (int ct = 0; ct < 8; ++ct) acc[ct] = (floatx4){0.f, 0.f, 0.f, 0.f};

#pragma unroll
  for (int seg = 0; seg < 4; ++seg) {
    const unsigned short* A = (seg < 2) ? agg : hv;
    const unsigned short* arp = A + (size_t)arow * D + quad * 8;
    const unsigned short* wseg = wt + (size_t)seg * D * D;
#pragma unroll
    for (int kst = 0; kst < 4; ++kst) {
      const short8 afrag = *(const short8*)(arp + kst * 32);
#pragma unroll
      for (int ct = 0; ct < 8; ++ct) {
        const short8 bfrag =
            *(const short8*)(wseg + (size_t)(ct * 16 + m) * D + kst * 32 + quad * 8);
        acc[ct] = __builtin_amdgcn_mfma_f32_16x16x32_bf16(afrag, bfrag, acc[ct], 0, 0, 0);
      }
    }
  }

  // epilogue: bias + relu, C/D layout col=lane&15, row=quad*4+reg
#pragma unroll
  for (int ct = 0; ct < 8; ++ct) {
    const int col = ct * 16 + m;
    const float b = brel[col];
#pragma unroll
    for (int i = 0; i < 4; ++i) {
      const int row = r0 + quad * 4 + i;
      if (row < N_NODES)
        outp[(size_t)row * D + col] = f2bf(fmaxf(acc[ct][i] + b, 0.f));
    }
  }
}

// ============= pool (segment ranges; batch sorted) + MLP head ===============
__device__ __forceinline__ int lb_search(const int* __restrict__ a, int n, int key) {
  int lo = 0, hi = n;
  while (lo < hi) {
    int m = (lo + hi) >> 1;
    if (a[m] < key) lo = m + 1; else hi = m;
  }
  return lo;
}

__global__ __launch_bounds__(256) void pool_head_kernel(
    const unsigned short* __restrict__ h, const int* __restrict__ batch,
    const float* __restrict__ W1, const float* __restrict__ b1,
    const float* __restrict__ W2, const float* __restrict__ b2,
    float* __restrict__ out) {
  __shared__ float sums_lds[16][128];
  __shared__ float pooled[128];
  __shared__ float hidden[128];
  __shared__ int range[2];
  const int g = blockIdx.x;
  const int t = threadIdx.x;
  if (t < 2) range[t] = lb_search(batch, N_NODES, g + t);
  __syncthreads();
  const int lo = range[0], hi = range[1];
  const int rg = t >> 4, cg = t & 15;   // 16 row-groups x 16 col-groups(8 cols each)
  float a0 = 0, a1 = 0, a2 = 0, a3 = 0, a4 = 0, a5 = 0, a6 = 0, a7 = 0;
  for (int n = lo + rg; n < hi; n += 16) {
    const uint4 v = *(const uint4*)&h[(size_t)n * D + cg * 8];
    a0 += __uint_as_float(v.x << 16); a1 += __uint_as_float(v.x & 0xffff0000u);
    a2 += __uint_as_float(v.y << 16); a3 += __uint_as_float(v.y & 0xffff0000u);
    a4 += __uint_as_float(v.z << 16); a5 += __uint_as_float(v.z & 0xffff0000u);
    a6 += __uint_as_float(v.w << 16); a7 += __uint_as_float(v.w & 0xffff0000u);
  }
  sums_lds[rg][cg * 8 + 0] = a0; sums_lds[rg][cg * 8 + 1] = a1;
  sums_lds[rg][cg * 8 + 2] = a2; sums_lds[rg][cg * 8 + 3] = a3;
  sums_lds[rg][cg * 8 + 4] = a4; sums_lds[rg][cg * 8 + 5] = a5;
  sums_lds[rg][cg * 8 + 6] = a6; sums_lds[rg][cg * 8 + 7] = a7;
  __syncthreads();
  if (t < 128) {
    float s = 0.f;
#pragma unroll
    for (int r = 0; r < 16; ++r) s += sums_lds[r][t];
    pooled[t] = s / fmaxf((float)(hi - lo), 1.f);
  }
  __syncthreads();
  if (t < 128) {
    float a = b1[t];
    for (int k = 0; k < D; ++k) a += pooled[k] * W1[k * D + t];
    hidden[t] = a;
  }
  __syncthreads();
  if (t < OUT_F) {
    float o = b2[t];
    for (int k = 0; k < D; ++k) o += hidden[k] * W2[k * OUT_F + t];
    out[(size_t)g * OUT_F + t] = o;
  }
}

// ============================== launch ======================================
extern "C" void kernel_launch(void* const* d_in, const int* in_sizes, int n_in,
                              void* d_out, int out_size, void* d_ws, size_t ws_size,
                              hipStream_t stream) {
  const float* x     = (const float*)d_in[0];
  const int*   ei    = (const int*)d_in[1];
  const int*   batch = (const int*)d_in[2];
  const float* Wrel  = (const float*)d_in[3];
  const float* brel  = (const float*)d_in[4];
  const float* Wroot = (const float*)d_in[5];
  const float* W1    = (const float*)d_in[6];
  const float* b1    = (const float*)d_in[7];
  const float* W2    = (const float*)d_in[8];
  const float* b2    = (const float*)d_in[9];
  float* out = (float*)d_out;

  const size_t ND = (size_t)N_NODES * D;
  unsigned short* aggA = (unsigned short*)d_ws;          // N*D bf16
  unsigned short* aggB = aggA + ND;                      // N*D bf16
  unsigned short* x16  = aggB + ND;                      // N*D bf16
  unsigned short* wt   = x16 + ND;                       // 3 * 4*D*D bf16
  int* rowptr = (int*)(wt + (size_t)N_LAYERS * 4 * D * D);  // N+1
  int* wpos   = rowptr + (N_NODES + 1);                  // N
  int* esrc   = wpos + N_NODES;                          // E
  int* bsum   = esrc + N_EDGES;                          // N_SCAN_BLOCKS

  const int* esrc_in = ei;
  const int* edst_in = ei + N_EDGES;

  // ---- CSR build ----
  hipMemsetAsync(wpos, 0, N_NODES * sizeof(int), stream);
  hist_kernel<<<(N_EDGES + 255) / 256, 256, 0, stream>>>(edst_in, wpos);
  scan1_kernel<<<N_SCAN_BLOCKS, SCAN_B, 0, stream>>>(wpos, rowptr, bsum);
  scan2_kernel<<<1, SCAN_B, 0, stream>>>(bsum);
  scan3_kernel<<<N_SCAN_BLOCKS + 1, SCAN_B, 0, stream>>>(rowptr, bsum, wpos);
  fill_kernel<<<(N_EDGES + 255) / 256, 256, 0, stream>>>(esrc_in, edst_in, wpos, esrc);

  // ---- prep bf16 ----
  cast_x_kernel<<<(int)((ND / 4 + 255) / 256), 256, 0, stream>>>(x, x16);
  prep_w_kernel<<<(N_LAYERS * 2 * D * D + 255) / 256, 256, 0, stream>>>(Wrel, Wroot, wt);

  // ---- 3 layers ----
  const int gemm_blocks = (N_NODES + 63) / 64;
  const int agg_blocks = (N_NODES * 16 + 255) / 256;
  // l0
  agg16_kernel<<<agg_blocks, 256, 0, stream>>>(x16, rowptr, esrc, aggA);
  gemm16_kernel<<<gemm_blocks, 256, 0, stream>>>(aggA, x16, wt, brel, aggA);
  // l1
  agg16_kernel<<<agg_blocks, 256, 0, stream>>>(aggA, rowptr, esrc, aggB);
  gemm16_kernel<<<gemm_blocks, 256, 0, stream>>>(aggB, aggA, wt + (size_t)4 * D * D,
                                                 brel + D, aggB);
  // l2
  agg16_kernel<<<agg_blocks, 256, 0, stream>>>(aggB, rowptr, esrc, aggA);
  gemm16_kernel<<<gemm_blocks, 256, 0, stream>>>(aggA, aggB, wt + (size_t)8 * D * D,
                                                 brel + 2 * D, aggA);

  pool_head_kernel<<<N_GRAPHS, 256, 0, stream>>>(aggA, batch, W1, b1, W2, b2, out);
}

// Round 4
// 455.299 us; speedup vs baseline: 11.5303x; 1.1372x over previous
//
#include <hip/hip_runtime.h>

#define N_NODES 50000
#define N_EDGES 800000
#define D 128
#define N_LAYERS 3
#define OUT_F 16
#define N_GRAPHS 128
#define SCAN_B 256
#define N_SCAN_BLOCKS ((N_NODES + SCAN_B - 1) / SCAN_B)  // 196

typedef __attribute__((ext_vector_type(8))) short short8;
typedef __attribute__((ext_vector_type(4))) float floatx4;

__device__ __forceinline__ unsigned short f2bf(float f) {
  unsigned int u = __float_as_uint(f);
  u += 0x7fff + ((u >> 16) & 1);   // RNE
  return (unsigned short)(u >> 16);
}
__device__ __forceinline__ float bf2f(unsigned short b) {
  return __uint_as_float(((unsigned int)b) << 16);
}

// ======================= CSR build (counting sort by dst) ===================
__global__ __launch_bounds__(256) void hist_kernel(
    const int* __restrict__ dst, int* __restrict__ cnt) {
  int e = blockIdx.x * 256 + threadIdx.x;
  if (e < N_EDGES) atomicAdd(&cnt[dst[e]], 1);
}

__global__ __launch_bounds__(SCAN_B) void scan1_kernel(
    const int* __restrict__ cnt, int* __restrict__ rowptr, int* __restrict__ bsum) {
  __shared__ int s[SCAN_B];
  int t = threadIdx.x;
  int i = blockIdx.x * SCAN_B + t;
  int v = (i < N_NODES) ? cnt[i] : 0;
  s[t] = v;
  __syncthreads();
  for (int off = 1; off < SCAN_B; off <<= 1) {
    int x = (t >= off) ? s[t - off] : 0;
    __syncthreads();
    s[t] += x;
    __syncthreads();
  }
  if (i < N_NODES) rowptr[i] = s[t] - v;
  if (t == SCAN_B - 1) bsum[blockIdx.x] = s[t];
}

__global__ __launch_bounds__(SCAN_B) void scan2_kernel(int* __restrict__ bsum) {
  __shared__ int s[SCAN_B];
  int t = threadIdx.x;
  int v = (t < N_SCAN_BLOCKS) ? bsum[t] : 0;
  s[t] = v;
  __syncthreads();
  for (int off = 1; off < SCAN_B; off <<= 1) {
    int x = (t >= off) ? s[t - off] : 0;
    __syncthreads();
    s[t] += x;
    __syncthreads();
  }
  if (t < N_SCAN_BLOCKS) bsum[t] = s[t] - v;
}

__global__ __launch_bounds__(SCAN_B) void scan3_kernel(
    int* __restrict__ rowptr, const int* __restrict__ bsum, int* __restrict__ wpos) {
  int i = blockIdx.x * SCAN_B + threadIdx.x;
  if (i < N_NODES) {
    int r = rowptr[i] + bsum[i >> 8];
    rowptr[i] = r;
    wpos[i] = r;
  }
  if (i == N_NODES) rowptr[N_NODES] = N_EDGES;
}

__global__ __launch_bounds__(256) void fill_kernel(
    const int* __restrict__ src, const int* __restrict__ dst,
    int* __restrict__ wpos, int* __restrict__ esrc) {
  int e = blockIdx.x * 256 + threadIdx.x;
  if (e >= N_EDGES) return;
  int p = atomicAdd(&wpos[dst[e]], 1);
  esrc[p] = src[e];
}

// ================= prep: cast x -> bf16; weights -> packed B-regs layout ====
__global__ __launch_bounds__(256) void cast_x_kernel(
    const float* __restrict__ x, unsigned short* __restrict__ x16) {
  int i = blockIdx.x * 256 + threadIdx.x;          // handles 4 floats
  if ((size_t)i * 4 >= (size_t)N_NODES * D) return;
  const float4 v = *(const float4*)&x[(size_t)i * 4];
  uint2 o;
  o.x = f2bf(v.x) | ((unsigned)f2bf(v.y) << 16);
  o.y = f2bf(v.z) | ((unsigned)f2bf(v.w) << 16);
  *(uint2*)&x16[(size_t)i * 4] = o;
}

// wt layout per layer: [n:128][kx:512], kx = {rel_hi k, rel_lo k, root_hi k, root_lo k}
__global__ __launch_bounds__(256) void prep_w_kernel(
    const float* __restrict__ Wrel, const float* __restrict__ Wroot,
    unsigned short* __restrict__ wt) {
  int idx = blockIdx.x * 256 + threadIdx.x;   // [l][mat][k][n], n innermost
  if (idx >= N_LAYERS * 2 * D * D) return;
  int n = idx & 127;
  int k = (idx >> 7) & 127;
  int mat = (idx >> 14) & 1;
  int l = idx >> 15;
  const float* W = mat ? Wroot : Wrel;
  float w = W[(size_t)l * D * D + k * D + n];
  unsigned short hi = f2bf(w);
  unsigned short lo = f2bf(w - bf2f(hi));
  unsigned short* base = wt + (size_t)l * D * 512 + (size_t)n * 512 + mat * 256;
  base[k] = hi;
  base[128 + k] = lo;
}

// ============ aggregate by gather (bf16 in, fp32 acc, bf16 out) =============
__global__ __launch_bounds__(256) void agg16_kernel(
    const unsigned short* __restrict__ h16, const int* __restrict__ rowptr,
    const int* __restrict__ esrc, unsigned short* __restrict__ agg) {
  int idx = blockIdx.x * 256 + threadIdx.x;
  int n = idx >> 4;
  int lane = idx & 15;
  if (n >= N_NODES) return;
  int beg = rowptr[n], end = rowptr[n + 1];
  float a0 = 0, a1 = 0, a2 = 0, a3 = 0, a4 = 0, a5 = 0, a6 = 0, a7 = 0;
  for (int e = beg; e < end; ++e) {
    int s = esrc[e];
    const uint4 v = *(const uint4*)&h16[(size_t)s * D + lane * 8];
    a0 += __uint_as_float(v.x << 16); a1 += __uint_as_float(v.x & 0xffff0000u);
    a2 += __uint_as_float(v.y << 16); a3 += __uint_as_float(v.y & 0xffff0000u);
    a4 += __uint_as_float(v.z << 16); a5 += __uint_as_float(v.z & 0xffff0000u);
    a6 += __uint_as_float(v.w << 16); a7 += __uint_as_float(v.w & 0xffff0000u);
  }
  uint4 o;
  o.x = f2bf(a0) | ((unsigned)f2bf(a1) << 16);
  o.y = f2bf(a2) | ((unsigned)f2bf(a3) << 16);
  o.z = f2bf(a4) | ((unsigned)f2bf(a5) << 16);
  o.w = f2bf(a6) | ((unsigned)f2bf(a7) << 16);
  *(uint4*)&agg[(size_t)n * D + lane * 8] = o;
}

// ====== MFMA GEMM, B-in-registers persistent: out = relu([agg|h]@W + b) =====
// 4 waves/block; wave w owns cols w*32..w*32+31 (2 col-tiles, 128 VGPR of B).
// Grid-stride over 3125 row-tiles of 16; A-frags double-buffered 1 tile ahead.
__global__ __launch_bounds__(256, 2) void gemm16_kernel(
    const unsigned short* agg, const unsigned short* hv,
    const unsigned short* __restrict__ wt, const float* __restrict__ brel,
    unsigned short* outp) {
  const int t = threadIdx.x;
  const int wave = t >> 6, lane = t & 63;
  const int m = lane & 15, quad = lane >> 4;
  const int col0 = wave * 32;

  // ---- load B fragments once (32 x 16B per lane) ----
  short8 bfrag[2][16];
#pragma unroll
  for (int ct = 0; ct < 2; ++ct) {
    const unsigned short* wp = wt + (size_t)(col0 + ct * 16 + m) * 512 + quad * 8;
#pragma unroll
    for (int kst = 0; kst < 16; ++kst)
      bfrag[ct][kst] = *(const short8*)(wp + kst * 32);
  }
  const float bias0 = brel[col0 + m];
  const float bias1 = brel[col0 + 16 + m];

  const int ntiles = N_NODES / 16;  // 3125 exact (50000 = 16*3125)
  short8 abuf[2][8];

  int tile = blockIdx.x;
  if (tile >= ntiles) return;
  {
    const unsigned short* ap = agg + (size_t)(tile * 16 + m) * D + quad * 8;
    const unsigned short* hp = hv + (size_t)(tile * 16 + m) * D + quad * 8;
#pragma unroll
    for (int i = 0; i < 4; ++i) {
      abuf[0][i] = *(const short8*)(ap + i * 32);
      abuf[0][4 + i] = *(const short8*)(hp + i * 32);
    }
  }
  int cur = 0;
  for (; tile < ntiles; tile += gridDim.x) {
    const int nxt = tile + gridDim.x;
    if (nxt < ntiles) {
      const unsigned short* ap = agg + (size_t)(nxt * 16 + m) * D + quad * 8;
      const unsigned short* hp = hv + (size_t)(nxt * 16 + m) * D + quad * 8;
#pragma unroll
      for (int i = 0; i < 4; ++i) {
        abuf[cur ^ 1][i] = *(const short8*)(ap + i * 32);
        abuf[cur ^ 1][4 + i] = *(const short8*)(hp + i * 32);
      }
    }
    floatx4 acc0 = {0.f, 0.f, 0.f, 0.f}, acc1 = {0.f, 0.f, 0.f, 0.f};
#pragma unroll
    for (int kst = 0; kst < 16; ++kst) {
      const short8 af = (kst < 8) ? abuf[cur][kst & 3] : abuf[cur][4 + (kst & 3)];
      acc0 = __builtin_amdgcn_mfma_f32_16x16x32_bf16(af, bfrag[0][kst], acc0, 0, 0, 0);
      acc1 = __builtin_amdgcn_mfma_f32_16x16x32_bf16(af, bfrag[1][kst], acc1, 0, 0, 0);
    }
    // epilogue: C/D layout col=lane&15, row=quad*4+reg
    const int r0 = tile * 16 + quad * 4;
#pragma unroll
    for (int i = 0; i < 4; ++i) {
      outp[(size_t)(r0 + i) * D + col0 + m] = f2bf(fmaxf(acc0[i] + bias0, 0.f));
      outp[(size_t)(r0 + i) * D + col0 + 16 + m] = f2bf(fmaxf(acc1[i] + bias1, 0.f));
    }
    cur ^= 1;
  }
}

// ============= pool (segment ranges; batch sorted) + MLP head ===============
__device__ __forceinline__ int lb_search(const int* __restrict__ a, int n, int key) {
  int lo = 0, hi = n;
  while (lo < hi) {
    int m = (lo + hi) >> 1;
    if (a[m] < key) lo = m + 1; else hi = m;
  }
  return lo;
}

__global__ __launch_bounds__(256) void pool_head_kernel(
    const unsigned short* __restrict__ h, const int* __restrict__ batch,
    const float* __restrict__ W1, const float* __restrict__ b1,
    const float* __restrict__ W2, const float* __restrict__ b2,
    float* __restrict__ out) {
  __shared__ float sums_lds[16][128];
  __shared__ float pooled[128];
  __shared__ float hidden[128];
  __shared__ int range[2];
  const int g = blockIdx.x;
  const int t = threadIdx.x;
  if (t < 2) range[t] = lb_search(batch, N_NODES, g + t);
  __syncthreads();
  const int lo = range[0], hi = range[1];
  const int rg = t >> 4, cg = t & 15;
  float a0 = 0, a1 = 0, a2 = 0, a3 = 0, a4 = 0, a5 = 0, a6 = 0, a7 = 0;
  for (int n = lo + rg; n < hi; n += 16) {
    const uint4 v = *(const uint4*)&h[(size_t)n * D + cg * 8];
    a0 += __uint_as_float(v.x << 16); a1 += __uint_as_float(v.x & 0xffff0000u);
    a2 += __uint_as_float(v.y << 16); a3 += __uint_as_float(v.y & 0xffff0000u);
    a4 += __uint_as_float(v.z << 16); a5 += __uint_as_float(v.z & 0xffff0000u);
    a6 += __uint_as_float(v.w << 16); a7 += __uint_as_float(v.w & 0xffff0000u);
  }
  sums_lds[rg][cg * 8 + 0] = a0; sums_lds[rg][cg * 8 + 1] = a1;
  sums_lds[rg][cg * 8 + 2] = a2; sums_lds[rg][cg * 8 + 3] = a3;
  sums_lds[rg][cg * 8 + 4] = a4; sums_lds[rg][cg * 8 + 5] = a5;
  sums_lds[rg][cg * 8 + 6] = a6; sums_lds[rg][cg * 8 + 7] = a7;
  __syncthreads();
  if (t < 128) {
    float s = 0.f;
#pragma unroll
    for (int r = 0; r < 16; ++r) s += sums_lds[r][t];
    pooled[t] = s / fmaxf((float)(hi - lo), 1.f);
  }
  __syncthreads();
  if (t < 128) {
    float a = b1[t];
    for (int k = 0; k < D; ++k) a += pooled[k] * W1[k * D + t];
    hidden[t] = a;
  }
  __syncthreads();
  if (t < OUT_F) {
    float o = b2[t];
    for (int k = 0; k < D; ++k) o += hidden[k] * W2[k * OUT_F + t];
    out[(size_t)g * OUT_F + t] = o;
  }
}

// ============================== launch ======================================
extern "C" void kernel_launch(void* const* d_in, const int* in_sizes, int n_in,
                              void* d_out, int out_size, void* d_ws, size_t ws_size,
                              hipStream_t stream) {
  const float* x     = (const float*)d_in[0];
  const int*   ei    = (const int*)d_in[1];
  const int*   batch = (const int*)d_in[2];
  const float* Wrel  = (const float*)d_in[3];
  const float* brel  = (const float*)d_in[4];
  const float* Wroot = (const float*)d_in[5];
  const float* W1    = (const float*)d_in[6];
  const float* b1    = (const float*)d_in[7];
  const float* W2    = (const float*)d_in[8];
  const float* b2    = (const float*)d_in[9];
  float* out = (float*)d_out;

  const size_t ND = (size_t)N_NODES * D;
  unsigned short* aggA = (unsigned short*)d_ws;          // N*D bf16
  unsigned short* aggB = aggA + ND;                      // N*D bf16
  unsigned short* x16  = aggB + ND;                      // N*D bf16
  unsigned short* wt   = x16 + ND;                       // 3 * 128 * 512 bf16
  int* rowptr = (int*)(wt + (size_t)N_LAYERS * D * 512); // N+1
  int* wpos   = rowptr + (N_NODES + 1);                  // N
  int* esrc   = wpos + N_NODES;                          // E
  int* bsum   = esrc + N_EDGES;                          // N_SCAN_BLOCKS

  const int* esrc_in = ei;
  const int* edst_in = ei + N_EDGES;

  // ---- CSR build ----
  hipMemsetAsync(wpos, 0, N_NODES * sizeof(int), stream);
  hist_kernel<<<(N_EDGES + 255) / 256, 256, 0, stream>>>(edst_in, wpos);
  scan1_kernel<<<N_SCAN_BLOCKS, SCAN_B, 0, stream>>>(wpos, rowptr, bsum);
  scan2_kernel<<<1, SCAN_B, 0, stream>>>(bsum);
  scan3_kernel<<<N_SCAN_BLOCKS + 1, SCAN_B, 0, stream>>>(rowptr, bsum, wpos);
  fill_kernel<<<(N_EDGES + 255) / 256, 256, 0, stream>>>(esrc_in, edst_in, wpos, esrc);

  // ---- prep bf16 ----
  cast_x_kernel<<<(int)((ND / 4 + 255) / 256), 256, 0, stream>>>(x, x16);
  prep_w_kernel<<<(N_LAYERS * 2 * D * D + 255) / 256, 256, 0, stream>>>(Wrel, Wroot, wt);

  // ---- 3 layers ----
  const int gemm_blocks = 512;   // 2 blocks/CU resident, grid-stride over 3125 tiles
  const int agg_blocks = (N_NODES * 16 + 255) / 256;
  agg16_kernel<<<agg_blocks, 256, 0, stream>>>(x16, rowptr, esrc, aggA);
  gemm16_kernel<<<gemm_blocks, 256, 0, stream>>>(aggA, x16, wt, brel, aggA);
  agg16_kernel<<<agg_blocks, 256, 0, stream>>>(aggA, rowptr, esrc, aggB);
  gemm16_kernel<<<gemm_blocks, 256, 0, stream>>>(aggB, aggA, wt + (size_t)D * 512,
                                                 brel + D, aggB);
  agg16_kernel<<<agg_blocks, 256, 0, stream>>>(aggB, rowptr, esrc, aggA);
  gemm16_kernel<<<gemm_blocks, 256, 0, stream>>>(aggA, aggB, wt + (size_t)2 * D * 512,
                                                 brel + 2 * D, aggA);

  pool_head_kernel<<<N_GRAPHS, 256, 0, stream>>>(aggA, batch, W1, b1, W2, b2, out);
}

// Round 5
// 384.785 us; speedup vs baseline: 13.6432x; 1.1833x over previous
//
#include <hip/hip_runtime.h>

#define N_NODES 50000
#define N_EDGES 800000
#define D 128
#define N_LAYERS 3
#define OUT_F 16
#define N_GRAPHS 128
#define NBUCK 391            // ceil(50000/128) buckets of 128 nodes
#define EPB 4096             // edges per partition block
#define NB3 ((N_EDGES + EPB - 1) / EPB)  // 196
#define CAP 4096             // max edges per bucket (mean ~2048, std ~45)

typedef __attribute__((ext_vector_type(8))) short short8;
typedef __attribute__((ext_vector_type(4))) float floatx4;

__device__ __forceinline__ unsigned short f2bf(float f) {
  unsigned int u = __float_as_uint(f);
  u += 0x7fff + ((u >> 16) & 1);   // RNE
  return (unsigned short)(u >> 16);
}
__device__ __forceinline__ float bf2f(unsigned short b) {
  return __uint_as_float(((unsigned int)b) << 16);
}

// ============== CSR build v2: bucketed counting sort, LDS-aggregated ========
// K1: per-block LDS histogram of dst>>7 -> global bucket counts
__global__ __launch_bounds__(256) void bucket_hist_kernel(
    const int* __restrict__ dst, int* __restrict__ bcnt) {
  __shared__ int hist[NBUCK];
  const int e0 = blockIdx.x * EPB;
  const int n = min(EPB, N_EDGES - e0);
  for (int i = threadIdx.x; i < NBUCK; i += 256) hist[i] = 0;
  __syncthreads();
  for (int i = threadIdx.x; i < n; i += 256) atomicAdd(&hist[dst[e0 + i] >> 7], 1);
  __syncthreads();
  for (int i = threadIdx.x; i < NBUCK; i += 256)
    if (hist[i]) atomicAdd(&bcnt[i], hist[i]);
}

// K2: scan 391 bucket counts -> bbase[392] + cursor init
__global__ __launch_bounds__(512) void bucket_scan_kernel(
    const int* __restrict__ bcnt, int* __restrict__ bbase,
    int* __restrict__ cursor, int* __restrict__ rowptr) {
  __shared__ int s[512];
  const int t = threadIdx.x;
  int v = (t < NBUCK) ? bcnt[t] : 0;
  s[t] = v;
  __syncthreads();
  for (int o = 1; o < 512; o <<= 1) {
    int x = (t >= o) ? s[t - o] : 0;
    __syncthreads();
    s[t] += x;
    __syncthreads();
  }
  if (t < NBUCK) { int ex = s[t] - v; bbase[t] = ex; cursor[t] = ex; }
  if (t == NBUCK - 1) bbase[NBUCK] = s[t];
  if (t == 0) rowptr[N_NODES] = N_EDGES;
}

// K3: partition edges into bucket-grouped pairs array; pk = (dst<<16)|src
__global__ __launch_bounds__(256) void partition_kernel(
    const int* __restrict__ src, const int* __restrict__ dst,
    int* __restrict__ cursor, unsigned* __restrict__ pairs) {
  __shared__ unsigned pk[EPB];
  __shared__ int hist[NBUCK];
  __shared__ int base_l[NBUCK];
  const int e0 = blockIdx.x * EPB;
  const int n = min(EPB, N_EDGES - e0);
  const int t = threadIdx.x;
  for (int i = t; i < NBUCK; i += 256) hist[i] = 0;
  __syncthreads();
  for (int i = t; i < n; i += 256) {
    int d = dst[e0 + i], s = src[e0 + i];
    pk[i] = ((unsigned)d << 16) | (unsigned)s;
    atomicAdd(&hist[d >> 7], 1);
  }
  __syncthreads();
  for (int i = t; i < NBUCK; i += 256)
    base_l[i] = hist[i] ? atomicAdd(&cursor[i], hist[i]) : 0;
  __syncthreads();
  for (int i = t; i < NBUCK; i += 256) hist[i] = base_l[i];  // reuse as cursor
  __syncthreads();
  for (int i = t; i < n; i += 256) {
    unsigned p = pk[i];
    int pos = atomicAdd(&hist[p >> 23], 1);
    pairs[pos] = p;
  }
}

// K4: per-bucket LDS counting sort by dst&127 -> esrc (coalesced) + rowptr
__global__ __launch_bounds__(256) void bucket_sort_kernel(
    const unsigned* __restrict__ pairs, const int* __restrict__ bbase,
    int* __restrict__ rowptr, int* __restrict__ esrc) {
  __shared__ unsigned pk[CAP];
  __shared__ int sorted[CAP];
  __shared__ int hist[128], off[128], cur[128];
  const int bkt = blockIdx.x;
  const int t = threadIdx.x;
  const int beg = bbase[bkt], end = bbase[bkt + 1];
  const int cnt = end - beg;
  if (t < 128) hist[t] = 0;
  __syncthreads();
  for (int i = t; i < cnt; i += 256) {
    unsigned p = pairs[beg + i];
    pk[i] = p;
    atomicAdd(&hist[(p >> 16) & 127], 1);
  }
  __syncthreads();
  if (t < 128) off[t] = hist[t];
  __syncthreads();
  for (int o = 1; o < 128; o <<= 1) {
    int x = (t < 128 && t >= o) ? off[t - o] : 0;
    __syncthreads();
    if (t < 128) off[t] += x;
    __syncthreads();
  }
  if (t < 128) {
    int ex = off[t] - hist[t];
    cur[t] = ex;
    int node = bkt * 128 + t;
    if (node < N_NODES) rowptr[node] = beg + ex;
  }
  __syncthreads();
  for (int i = t; i < cnt; i += 256) {
    unsigned p = pk[i];
    int pos = atomicAdd(&cur[(p >> 16) & 127], 1);
    sorted[pos] = (int)(p & 0xFFFFu);
  }
  __syncthreads();
  for (int i = t; i < cnt; i += 256) esrc[beg + i] = sorted[i];
}

// ================= prep: cast x -> bf16; weights -> packed B-regs layout ====
__global__ __launch_bounds__(256) void cast_x_kernel(
    const float* __restrict__ x, unsigned short* __restrict__ x16) {
  int i = blockIdx.x * 256 + threadIdx.x;          // handles 4 floats
  if ((size_t)i * 4 >= (size_t)N_NODES * D) return;
  const float4 v = *(const float4*)&x[(size_t)i * 4];
  uint2 o;
  o.x = f2bf(v.x) | ((unsigned)f2bf(v.y) << 16);
  o.y = f2bf(v.z) | ((unsigned)f2bf(v.w) << 16);
  *(uint2*)&x16[(size_t)i * 4] = o;
}

// wt layout per layer: [n:128][kx:512], kx = {rel_hi k, rel_lo k, root_hi k, root_lo k}
__global__ __launch_bounds__(256) void prep_w_kernel(
    const float* __restrict__ Wrel, const float* __restrict__ Wroot,
    unsigned short* __restrict__ wt) {
  int idx = blockIdx.x * 256 + threadIdx.x;
  if (idx >= N_LAYERS * 2 * D * D) return;
  int n = idx & 127;
  int k = (idx >> 7) & 127;
  int mat = (idx >> 14) & 1;
  int l = idx >> 15;
  const float* W = mat ? Wroot : Wrel;
  float w = W[(size_t)l * D * D + k * D + n];
  unsigned short hi = f2bf(w);
  unsigned short lo = f2bf(w - bf2f(hi));
  unsigned short* base = wt + (size_t)l * D * 512 + (size_t)n * 512 + mat * 256;
  base[k] = hi;
  base[128 + k] = lo;
}

// ============ aggregate: one wave per node, scalar edge loop ================
__global__ __launch_bounds__(256) void agg16_kernel(
    const unsigned short* __restrict__ h16, const int* __restrict__ rowptr,
    const int* __restrict__ esrc, unsigned short* __restrict__ agg) {
  const int idx = blockIdx.x * 256 + threadIdx.x;
  const int n = __builtin_amdgcn_readfirstlane(idx >> 6);
  const int lane = threadIdx.x & 63;
  if (n >= N_NODES) return;
  const int beg = rowptr[n], end = rowptr[n + 1];
  float a0 = 0.f, a1 = 0.f;
  int e = beg;
  for (; e + 2 <= end; e += 2) {
    const int s0 = esrc[e], s1 = esrc[e + 1];
    const unsigned v0 = *(const unsigned*)&h16[(size_t)s0 * D + lane * 2];
    const unsigned v1 = *(const unsigned*)&h16[(size_t)s1 * D + lane * 2];
    a0 += __uint_as_float(v0 << 16) + __uint_as_float(v1 << 16);
    a1 += __uint_as_float(v0 & 0xffff0000u) + __uint_as_float(v1 & 0xffff0000u);
  }
  if (e < end) {
    const int s0 = esrc[e];
    const unsigned v0 = *(const unsigned*)&h16[(size_t)s0 * D + lane * 2];
    a0 += __uint_as_float(v0 << 16);
    a1 += __uint_as_float(v0 & 0xffff0000u);
  }
  *(unsigned*)&agg[(size_t)n * D + lane * 2] =
      f2bf(a0) | ((unsigned)f2bf(a1) << 16);
}

// ====== MFMA GEMM, B-in-registers persistent: out = relu([agg|h]@W + b) =====
__global__ __launch_bounds__(256, 2) void gemm16_kernel(
    const unsigned short* agg, const unsigned short* hv,
    const unsigned short* __restrict__ wt, const float* __restrict__ brel,
    unsigned short* outp) {
  const int t = threadIdx.x;
  const int wave = t >> 6, lane = t & 63;
  const int m = lane & 15, quad = lane >> 4;
  const int col0 = wave * 32;

  short8 bfrag[2][16];
#pragma unroll
  for (int ct = 0; ct < 2; ++ct) {
    const unsigned short* wp = wt + (size_t)(col0 + ct * 16 + m) * 512 + quad * 8;
#pragma unroll
    for (int kst = 0; kst < 16; ++kst)
      bfrag[ct][kst] = *(const short8*)(wp + kst * 32);
  }
  const float bias0 = brel[col0 + m];
  const float bias1 = brel[col0 + 16 + m];

  const int ntiles = N_NODES / 16;  // 3125 exact
  short8 abuf[2][8];

  int tile = blockIdx.x;
  if (tile >= ntiles) return;
  {
    const unsigned short* ap = agg + (size_t)(tile * 16 + m) * D + quad * 8;
    const unsigned short* hp = hv + (size_t)(tile * 16 + m) * D + quad * 8;
#pragma unroll
    for (int i = 0; i < 4; ++i) {
      abuf[0][i] = *(const short8*)(ap + i * 32);
      abuf[0][4 + i] = *(const short8*)(hp + i * 32);
    }
  }
  int cur = 0;
  for (; tile < ntiles; tile += gridDim.x) {
    const int nxt = tile + gridDim.x;
    if (nxt < ntiles) {
      const unsigned short* ap = agg + (size_t)(nxt * 16 + m) * D + quad * 8;
      const unsigned short* hp = hv + (size_t)(nxt * 16 + m) * D + quad * 8;
#pragma unroll
      for (int i = 0; i < 4; ++i) {
        abuf[cur ^ 1][i] = *(const short8*)(ap + i * 32);
        abuf[cur ^ 1][4 + i] = *(const short8*)(hp + i * 32);
      }
    }
    floatx4 acc0 = {0.f, 0.f, 0.f, 0.f}, acc1 = {0.f, 0.f, 0.f, 0.f};
#pragma unroll
    for (int kst = 0; kst < 16; ++kst) {
      const short8 af = (kst < 8) ? abuf[cur][kst & 3] : abuf[cur][4 + (kst & 3)];
      acc0 = __builtin_amdgcn_mfma_f32_16x16x32_bf16(af, bfrag[0][kst], acc0, 0, 0, 0);
      acc1 = __builtin_amdgcn_mfma_f32_16x16x32_bf16(af, bfrag[1][kst], acc1, 0, 0, 0);
    }
    const int r0 = tile * 16 + quad * 4;
#pragma unroll
    for (int i = 0; i < 4; ++i) {
      outp[(size_t)(r0 + i) * D + col0 + m] = f2bf(fmaxf(acc0[i] + bias0, 0.f));
      outp[(size_t)(r0 + i) * D + col0 + 16 + m] = f2bf(fmaxf(acc1[i] + bias1, 0.f));
    }
    cur ^= 1;
  }
}

// ============= pool (segment ranges; batch sorted) + MLP head ===============
__device__ __forceinline__ int lb_search(const int* __restrict__ a, int n, int key) {
  int lo = 0, hi = n;
  while (lo < hi) {
    int m = (lo + hi) >> 1;
    if (a[m] < key) lo = m + 1; else hi = m;
  }
  return lo;
}

__global__ __launch_bounds__(256) void pool_head_kernel(
    const unsigned short* __restrict__ h, const int* __restrict__ batch,
    const float* __restrict__ W1, const float* __restrict__ b1,
    const float* __restrict__ W2, const float* __restrict__ b2,
    float* __restrict__ out) {
  __shared__ float sums_lds[16][128];
  __shared__ float pooled[128];
  __shared__ float hidden[128];
  __shared__ int range[2];
  const int g = blockIdx.x;
  const int t = threadIdx.x;
  if (t < 2) range[t] = lb_search(batch, N_NODES, g + t);
  __syncthreads();
  const int lo = range[0], hi = range[1];
  const int rg = t >> 4, cg = t & 15;
  float a0 = 0, a1 = 0, a2 = 0, a3 = 0, a4 = 0, a5 = 0, a6 = 0, a7 = 0;
  for (int n = lo + rg; n < hi; n += 16) {
    const uint4 v = *(const uint4*)&h[(size_t)n * D + cg * 8];
    a0 += __uint_as_float(v.x << 16); a1 += __uint_as_float(v.x & 0xffff0000u);
    a2 += __uint_as_float(v.y << 16); a3 += __uint_as_float(v.y & 0xffff0000u);
    a4 += __uint_as_float(v.z << 16); a5 += __uint_as_float(v.z & 0xffff0000u);
    a6 += __uint_as_float(v.w << 16); a7 += __uint_as_float(v.w & 0xffff0000u);
  }
  sums_lds[rg][cg * 8 + 0] = a0; sums_lds[rg][cg * 8 + 1] = a1;
  sums_lds[rg][cg * 8 + 2] = a2; sums_lds[rg][cg * 8 + 3] = a3;
  sums_lds[rg][cg * 8 + 4] = a4; sums_lds[rg][cg * 8 + 5] = a5;
  sums_lds[rg][cg * 8 + 6] = a6; sums_lds[rg][cg * 8 + 7] = a7;
  __syncthreads();
  if (t < 128) {
    float s = 0.f;
#pragma unroll
    for (int r = 0; r < 16; ++r) s += sums_lds[r][t];
    pooled[t] = s / fmaxf((float)(hi - lo), 1.f);
  }
  __syncthreads();
  if (t < 128) {
    float a = b1[t];
    for (int k = 0; k < D; ++k) a += pooled[k] * W1[k * D + t];
    hidden[t] = a;
  }
  __syncthreads();
  if (t < OUT_F) {
    float o = b2[t];
    for (int k = 0; k < D; ++k) o += hidden[k] * W2[k * OUT_F + t];
    out[(size_t)g * OUT_F + t] = o;
  }
}

// ============================== launch ======================================
extern "C" void kernel_launch(void* const* d_in, const int* in_sizes, int n_in,
                              void* d_out, int out_size, void* d_ws, size_t ws_size,
                              hipStream_t stream) {
  const float* x     = (const float*)d_in[0];
  const int*   ei    = (const int*)d_in[1];
  const int*   batch = (const int*)d_in[2];
  const float* Wrel  = (const float*)d_in[3];
  const float* brel  = (const float*)d_in[4];
  const float* Wroot = (const float*)d_in[5];
  const float* W1    = (const float*)d_in[6];
  const float* b1    = (const float*)d_in[7];
  const float* W2    = (const float*)d_in[8];
  const float* b2    = (const float*)d_in[9];
  float* out = (float*)d_out;

  const size_t ND = (size_t)N_NODES * D;
  unsigned short* aggA = (unsigned short*)d_ws;          // N*D bf16
  unsigned short* aggB = aggA + ND;                      // N*D bf16
  unsigned short* x16  = aggB + ND;                      // N*D bf16
  unsigned short* wt   = x16 + ND;                       // 3*128*512 bf16
  int* rowptr = (int*)(wt + (size_t)N_LAYERS * D * 512); // N+1
  int* esrc   = rowptr + (N_NODES + 1);                  // E
  unsigned* pairs = (unsigned*)(esrc + N_EDGES);         // E
  int* bcnt   = (int*)(pairs + N_EDGES);                 // NBUCK
  int* bbase  = bcnt + NBUCK;                            // NBUCK+1
  int* cursor = bbase + NBUCK + 1;                       // NBUCK

  const int* esrc_in = ei;
  const int* edst_in = ei + N_EDGES;

  // ---- CSR build v2 ----
  hipMemsetAsync(bcnt, 0, NBUCK * sizeof(int), stream);
  bucket_hist_kernel<<<NB3, 256, 0, stream>>>(edst_in, bcnt);
  bucket_scan_kernel<<<1, 512, 0, stream>>>(bcnt, bbase, cursor, rowptr);
  partition_kernel<<<NB3, 256, 0, stream>>>(esrc_in, edst_in, cursor, pairs);
  bucket_sort_kernel<<<NBUCK, 256, 0, stream>>>(pairs, bbase, rowptr, esrc);

  // ---- prep bf16 ----
  cast_x_kernel<<<(int)((ND / 4 + 255) / 256), 256, 0, stream>>>(x, x16);
  prep_w_kernel<<<(N_LAYERS * 2 * D * D + 255) / 256, 256, 0, stream>>>(Wrel, Wroot, wt);

  // ---- 3 layers ----
  const int gemm_blocks = 512;
  const int agg_blocks = (N_NODES * 64 + 255) / 256;  // 12500
  agg16_kernel<<<agg_blocks, 256, 0, stream>>>(x16, rowptr, esrc, aggA);
  gemm16_kernel<<<gemm_blocks, 256, 0, stream>>>(aggA, x16, wt, brel, aggA);
  agg16_kernel<<<agg_blocks, 256, 0, stream>>>(aggA, rowptr, esrc, aggB);
  gemm16_kernel<<<gemm_blocks, 256, 0, stream>>>(aggB, aggA, wt + (size_t)D * 512,
                                                 brel + D, aggB);
  agg16_kernel<<<agg_blocks, 256, 0, stream>>>(aggB, rowptr, esrc, aggA);
  gemm16_kernel<<<gemm_blocks, 256, 0, stream>>>(aggA, aggB, wt + (size_t)2 * D * 512,
                                                 brel + 2 * D, aggA);

  pool_head_kernel<<<N_GRAPHS, 256, 0, stream>>>(aggA, batch, W1, b1, W2, b2, out);
}

// Round 6
// 344.771 us; speedup vs baseline: 15.2266x; 1.1161x over previous
//
#include <hip/hip_runtime.h>

#define N_NODES 50000
#define N_EDGES 800000
#define D 128
#define N_LAYERS 3
#define OUT_F 16
#define N_GRAPHS 128
#define NBUCK 391            // ceil(50000/128) buckets of 128 nodes
#define EPB 4096             // edges per partition block
#define NB3 ((N_EDGES + EPB - 1) / EPB)  // 196
#define CAP 4096             // max edges per bucket (mean ~2048)
#define NT32 ((N_NODES + 31) / 32)       // 1563 row-tiles of 32

typedef __attribute__((ext_vector_type(8))) short short8;
typedef __attribute__((ext_vector_type(16))) float floatx16;

__device__ __forceinline__ unsigned short f2bf(float f) {
  unsigned int u = __float_as_uint(f);
  u += 0x7fff + ((u >> 16) & 1);   // RNE
  return (unsigned short)(u >> 16);
}
__device__ __forceinline__ float bf2f(unsigned short b) {
  return __uint_as_float(((unsigned int)b) << 16);
}

// ============== CSR build: bucketed counting sort, LDS-aggregated ===========
__global__ __launch_bounds__(256) void bucket_hist_kernel(
    const int* __restrict__ dst, int* __restrict__ bcnt) {
  __shared__ int hist[NBUCK];
  const int e0 = blockIdx.x * EPB;
  const int n = min(EPB, N_EDGES - e0);
  for (int i = threadIdx.x; i < NBUCK; i += 256) hist[i] = 0;
  __syncthreads();
  for (int i = threadIdx.x; i < n; i += 256) atomicAdd(&hist[dst[e0 + i] >> 7], 1);
  __syncthreads();
  for (int i = threadIdx.x; i < NBUCK; i += 256)
    if (hist[i]) atomicAdd(&bcnt[i], hist[i]);
}

__global__ __launch_bounds__(512) void bucket_scan_kernel(
    const int* __restrict__ bcnt, int* __restrict__ bbase,
    int* __restrict__ cursor, int* __restrict__ rowptr) {
  __shared__ int s[512];
  const int t = threadIdx.x;
  int v = (t < NBUCK) ? bcnt[t] : 0;
  s[t] = v;
  __syncthreads();
  for (int o = 1; o < 512; o <<= 1) {
    int x = (t >= o) ? s[t - o] : 0;
    __syncthreads();
    s[t] += x;
    __syncthreads();
  }
  if (t < NBUCK) { int ex = s[t] - v; bbase[t] = ex; cursor[t] = ex; }
  if (t == NBUCK - 1) bbase[NBUCK] = s[t];
  if (t == 0) rowptr[N_NODES] = N_EDGES;
}

__global__ __launch_bounds__(256) void partition_kernel(
    const int* __restrict__ src, const int* __restrict__ dst,
    int* __restrict__ cursor, unsigned* __restrict__ pairs) {
  __shared__ unsigned pk[EPB];
  __shared__ int hist[NBUCK];
  __shared__ int base_l[NBUCK];
  const int e0 = blockIdx.x * EPB;
  const int n = min(EPB, N_EDGES - e0);
  const int t = threadIdx.x;
  for (int i = t; i < NBUCK; i += 256) hist[i] = 0;
  __syncthreads();
  for (int i = t; i < n; i += 256) {
    int d = dst[e0 + i], s = src[e0 + i];
    pk[i] = ((unsigned)d << 16) | (unsigned)s;
    atomicAdd(&hist[d >> 7], 1);
  }
  __syncthreads();
  for (int i = t; i < NBUCK; i += 256)
    base_l[i] = hist[i] ? atomicAdd(&cursor[i], hist[i]) : 0;
  __syncthreads();
  for (int i = t; i < NBUCK; i += 256) hist[i] = base_l[i];
  __syncthreads();
  for (int i = t; i < n; i += 256) {
    unsigned p = pk[i];
    int pos = atomicAdd(&hist[p >> 23], 1);
    pairs[pos] = p;
  }
}

__global__ __launch_bounds__(256) void bucket_sort_kernel(
    const unsigned* __restrict__ pairs, const int* __restrict__ bbase,
    int* __restrict__ rowptr, int* __restrict__ esrc) {
  __shared__ unsigned pk[CAP];
  __shared__ int sorted[CAP];
  __shared__ int hist[128], off[128], cur[128];
  const int bkt = blockIdx.x;
  const int t = threadIdx.x;
  const int beg = bbase[bkt], end = bbase[bkt + 1];
  const int cnt = end - beg;
  if (t < 128) hist[t] = 0;
  __syncthreads();
  for (int i = t; i < cnt; i += 256) {
    unsigned p = pairs[beg + i];
    pk[i] = p;
    atomicAdd(&hist[(p >> 16) & 127], 1);
  }
  __syncthreads();
  if (t < 128) off[t] = hist[t];
  __syncthreads();
  for (int o = 1; o < 128; o <<= 1) {
    int x = (t < 128 && t >= o) ? off[t - o] : 0;
    __syncthreads();
    if (t < 128) off[t] += x;
    __syncthreads();
  }
  if (t < 128) {
    int ex = off[t] - hist[t];
    cur[t] = ex;
    int node = bkt * 128 + t;
    if (node < N_NODES) rowptr[node] = beg + ex;
  }
  __syncthreads();
  for (int i = t; i < cnt; i += 256) {
    unsigned p = pk[i];
    int pos = atomicAdd(&cur[(p >> 16) & 127], 1);
    sorted[pos] = (int)(p & 0xFFFFu);
  }
  __syncthreads();
  for (int i = t; i < cnt; i += 256) esrc[beg + i] = sorted[i];
}

// ================= prep: cast x -> bf16; weights -> MFMA-frag layout ========
__global__ __launch_bounds__(256) void cast_x_kernel(
    const float* __restrict__ x, unsigned short* __restrict__ x16) {
  int i = blockIdx.x * 256 + threadIdx.x;          // handles 4 floats
  if ((size_t)i * 4 >= (size_t)N_NODES * D) return;
  const float4 v = *(const float4*)&x[(size_t)i * 4];
  uint2 o;
  o.x = f2bf(v.x) | ((unsigned)f2bf(v.y) << 16);
  o.y = f2bf(v.z) | ((unsigned)f2bf(v.w) << 16);
  *(uint2*)&x16[(size_t)i * 4] = o;
}

// wt layout: [l][half:2][nt:2][kst:32][lane:64][j:8] bf16 (1 KB per frag).
// Element (lane,j) = B[kx][n], n = half*64+nt*32+(lane&31),
// kx = kst*16+(lane>>5)*8+j; kx = seg*128+k, segs {rel_hi,rel_lo,root_hi,root_lo}.
__global__ __launch_bounds__(256) void prep_w_kernel(
    const float* __restrict__ Wrel, const float* __restrict__ Wroot,
    unsigned short* __restrict__ wt) {
  int idx = blockIdx.x * 256 + threadIdx.x;   // 3*2*2*32*64 = 24576 threads
  if (idx >= N_LAYERS * 2 * 2 * 32 * 64) return;
  const int lane = idx & 63;
  const int kst = (idx >> 6) & 31;
  const int nt = (idx >> 11) & 1;
  const int half = (idx >> 12) & 1;
  const int l = idx >> 13;
  const int n = half * 64 + nt * 32 + (lane & 31);
  const int kx0 = kst * 16 + (lane >> 5) * 8;
  const int seg = kx0 >> 7;           // same seg for all 8 j
  const int k0 = kx0 & 127;
  const int mat = seg >> 1, lo = seg & 1;
  const float* W = (mat ? Wroot : Wrel) + (size_t)l * D * D;
  unsigned short v[8];
#pragma unroll
  for (int j = 0; j < 8; ++j) {
    float w = W[(size_t)(k0 + j) * D + n];
    unsigned short hi = f2bf(w);
    v[j] = lo ? f2bf(w - bf2f(hi)) : hi;
  }
  unsigned short* dstp =
      wt + ((size_t)l * 128 + (half * 2 + nt) * 32 + kst) * 512 + lane * 8;
  *(uint4*)dstp = *(const uint4*)v;
}

// ============ aggregate: one wave per node, scalar edge loop ================
__global__ __launch_bounds__(256) void agg16_kernel(
    const unsigned short* __restrict__ h16, const int* __restrict__ rowptr,
    const int* __restrict__ esrc, unsigned short* __restrict__ agg) {
  const int idx = blockIdx.x * 256 + threadIdx.x;
  const int n = __builtin_amdgcn_readfirstlane(idx >> 6);
  const int lane = threadIdx.x & 63;
  if (n >= N_NODES) return;
  const int beg = rowptr[n], end = rowptr[n + 1];
  float a0 = 0.f, a1 = 0.f;
  int e = beg;
  for (; e + 2 <= end; e += 2) {
    const int s0 = esrc[e], s1 = esrc[e + 1];
    const unsigned v0 = *(const unsigned*)&h16[(size_t)s0 * D + lane * 2];
    const unsigned v1 = *(const unsigned*)&h16[(size_t)s1 * D + lane * 2];
    a0 += __uint_as_float(v0 << 16) + __uint_as_float(v1 << 16);
    a1 += __uint_as_float(v0 & 0xffff0000u) + __uint_as_float(v1 & 0xffff0000u);
  }
  if (e < end) {
    const int s0 = esrc[e];
    const unsigned v0 = *(const unsigned*)&h16[(size_t)s0 * D + lane * 2];
    a0 += __uint_as_float(v0 << 16);
    a1 += __uint_as_float(v0 & 0xffff0000u);
  }
  *(unsigned*)&agg[(size_t)n * D + lane * 2] =
      f2bf(a0) | ((unsigned)f2bf(a1) << 16);
}

// ====== MFMA 32x32x16 GEMM, B staged in LDS (frag-order, conflict-free) =====
// grid = (196, 2); blockIdx.y = col half. 4 waves/block; wave handles whole
// 32-row tiles (grid-stride), 64 cols (2 n-tiles of 32). Out-of-place.
__global__ __launch_bounds__(256, 2) void gemm32_kernel(
    const unsigned short* __restrict__ agg, const unsigned short* __restrict__ hv,
    const unsigned short* __restrict__ wt, const float* __restrict__ brel,
    unsigned short* __restrict__ outp) {
  __shared__ unsigned short blds[32768];   // 64 KB: this half's 64 frag-sets
  const int t = threadIdx.x;
  const int wave = t >> 6, lane = t & 63;
  const int half = blockIdx.y;

  // stage B: linear 64 KB copy (coalesced dwordx4)
  {
    const unsigned short* wsrc = wt + (size_t)half * 32768;
#pragma unroll
    for (int i = 0; i < 16; ++i) {
      const int idx = t + i * 256;   // 0..4095 uint4 units
      *(uint4*)&blds[idx * 8] = *(const uint4*)&wsrc[idx * 8];
    }
  }
  __syncthreads();

  const int r_lane = lane & 31;       // A row within tile / C col within ntile
  const int hseg = lane >> 5;         // 0/1
  const float bias0 = brel[half * 64 + r_lane];
  const float bias1 = brel[half * 64 + 32 + r_lane];

  const int nwaves = gridDim.x * 4;
  for (int tile = blockIdx.x * 4 + wave; tile < NT32; tile += nwaves) {
    const int r0 = tile * 32;
    int arow = r0 + r_lane;
    if (arow >= N_NODES) arow = N_NODES - 1;
    const unsigned short* ap = agg + (size_t)arow * D + hseg * 8;
    const unsigned short* hp = hv + (size_t)arow * D + hseg * 8;
    short8 ag[8], hh[8];
#pragma unroll
    for (int i = 0; i < 8; ++i) {
      ag[i] = *(const short8*)(ap + i * 16);
      hh[i] = *(const short8*)(hp + i * 16);
    }
    floatx16 acc0 = {0.f}, acc1 = {0.f};
#pragma unroll
    for (int kst = 0; kst < 32; ++kst) {
      const short8 af = (kst < 16) ? ag[kst & 7] : hh[kst & 7];
      const short8 b0 = *(const short8*)&blds[(size_t)kst * 512 + lane * 8];
      const short8 b1 = *(const short8*)&blds[(size_t)(32 + kst) * 512 + lane * 8];
      acc0 = __builtin_amdgcn_mfma_f32_32x32x16_bf16(af, b0, acc0, 0, 0, 0);
      acc1 = __builtin_amdgcn_mfma_f32_32x32x16_bf16(af, b1, acc1, 0, 0, 0);
    }
    // epilogue: col = half*64 + nt*32 + (lane&31); row = (reg&3)+8*(reg>>2)+4*hseg
    const int cb = half * 64 + r_lane;
#pragma unroll
    for (int reg = 0; reg < 16; ++reg) {
      const int row = r0 + (reg & 3) + 8 * (reg >> 2) + 4 * hseg;
      if (row < N_NODES) {
        outp[(size_t)row * D + cb] = f2bf(fmaxf(acc0[reg] + bias0, 0.f));
        outp[(size_t)row * D + cb + 32] = f2bf(fmaxf(acc1[reg] + bias1, 0.f));
      }
    }
  }
}

// ============= pool (segment ranges; batch sorted) + MLP head ===============
__device__ __forceinline__ int lb_search(const int* __restrict__ a, int n, int key) {
  int lo = 0, hi = n;
  while (lo < hi) {
    int m = (lo + hi) >> 1;
    if (a[m] < key) lo = m + 1; else hi = m;
  }
  return lo;
}

__global__ __launch_bounds__(256) void pool_head_kernel(
    const unsigned short* __restrict__ h, const int* __restrict__ batch,
    const float* __restrict__ W1, const float* __restrict__ b1,
    const float* __restrict__ W2, const float* __restrict__ b2,
    float* __restrict__ out) {
  __shared__ float sums_lds[16][128];
  __shared__ float pooled[128];
  __shared__ float hidden[128];
  __shared__ int range[2];
  const int g = blockIdx.x;
  const int t = threadIdx.x;
  if (t < 2) range[t] = lb_search(batch, N_NODES, g + t);
  __syncthreads();
  const int lo = range[0], hi = range[1];
  const int rg = t >> 4, cg = t & 15;
  float a0 = 0, a1 = 0, a2 = 0, a3 = 0, a4 = 0, a5 = 0, a6 = 0, a7 = 0;
  for (int n = lo + rg; n < hi; n += 16) {
    const uint4 v = *(const uint4*)&h[(size_t)n * D + cg * 8];
    a0 += __uint_as_float(v.x << 16); a1 += __uint_as_float(v.x & 0xffff0000u);
    a2 += __uint_as_float(v.y << 16); a3 += __uint_as_float(v.y & 0xffff0000u);
    a4 += __uint_as_float(v.z << 16); a5 += __uint_as_float(v.z & 0xffff0000u);
    a6 += __uint_as_float(v.w << 16); a7 += __uint_as_float(v.w & 0xffff0000u);
  }
  sums_lds[rg][cg * 8 + 0] = a0; sums_lds[rg][cg * 8 + 1] = a1;
  sums_lds[rg][cg * 8 + 2] = a2; sums_lds[rg][cg * 8 + 3] = a3;
  sums_lds[rg][cg * 8 + 4] = a4; sums_lds[rg][cg * 8 + 5] = a5;
  sums_lds[rg][cg * 8 + 6] = a6; sums_lds[rg][cg * 8 + 7] = a7;
  __syncthreads();
  if (t < 128) {
    float s = 0.f;
#pragma unroll
    for (int r = 0; r < 16; ++r) s += sums_lds[r][t];
    pooled[t] = s / fmaxf((float)(hi - lo), 1.f);
  }
  __syncthreads();
  if (t < 128) {
    float a = b1[t];
    for (int k = 0; k < D; ++k) a += pooled[k] * W1[k * D + t];
    hidden[t] = a;
  }
  __syncthreads();
  if (t < OUT_F) {
    float o = b2[t];
    for (int k = 0; k < D; ++k) o += hidden[k] * W2[k * OUT_F + t];
    out[(size_t)g * OUT_F + t] = o;
  }
}

// ============================== launch ======================================
extern "C" void kernel_launch(void* const* d_in, const int* in_sizes, int n_in,
                              void* d_out, int out_size, void* d_ws, size_t ws_size,
                              hipStream_t stream) {
  const float* x     = (const float*)d_in[0];
  const int*   ei    = (const int*)d_in[1];
  const int*   batch = (const int*)d_in[2];
  const float* Wrel  = (const float*)d_in[3];
  const float* brel  = (const float*)d_in[4];
  const float* Wroot = (const float*)d_in[5];
  const float* W1    = (const float*)d_in[6];
  const float* b1    = (const float*)d_in[7];
  const float* W2    = (const float*)d_in[8];
  const float* b2    = (const float*)d_in[9];
  float* out = (float*)d_out;

  const size_t ND = (size_t)N_NODES * D;
  unsigned short* bufA = (unsigned short*)d_ws;          // N*D bf16
  unsigned short* bufB = bufA + ND;                      // N*D bf16
  unsigned short* bufC = bufB + ND;                      // N*D bf16 (x16)
  unsigned short* wt   = bufC + ND;                      // 3*128*512 bf16
  int* rowptr = (int*)(wt + (size_t)N_LAYERS * D * 512); // N+1
  int* esrc   = rowptr + (N_NODES + 1);                  // E
  unsigned* pairs = (unsigned*)(esrc + N_EDGES);         // E
  int* bcnt   = (int*)(pairs + N_EDGES);                 // NBUCK
  int* bbase  = bcnt + NBUCK;                            // NBUCK+1
  int* cursor = bbase + NBUCK + 1;                       // NBUCK

  const int* esrc_in = ei;
  const int* edst_in = ei + N_EDGES;

  // ---- CSR build ----
  hipMemsetAsync(bcnt, 0, NBUCK * sizeof(int), stream);
  bucket_hist_kernel<<<NB3, 256, 0, stream>>>(edst_in, bcnt);
  bucket_scan_kernel<<<1, 512, 0, stream>>>(bcnt, bbase, cursor, rowptr);
  partition_kernel<<<NB3, 256, 0, stream>>>(esrc_in, edst_in, cursor, pairs);
  bucket_sort_kernel<<<NBUCK, 256, 0, stream>>>(pairs, bbase, rowptr, esrc);

  // ---- prep bf16 ----
  cast_x_kernel<<<(int)((ND / 4 + 255) / 256), 256, 0, stream>>>(x, bufC);
  prep_w_kernel<<<(N_LAYERS * 2 * 2 * 32 * 64 + 255) / 256, 256, 0, stream>>>(
      Wrel, Wroot, wt);

  // ---- 3 layers (out-of-place buffer rotation) ----
  const dim3 ggrid(196, 2);
  const int agg_blocks = (N_NODES * 64 + 255) / 256;  // 12500
  const size_t WL = (size_t)128 * 512;                // wt shorts per layer
  // l0: agg(x16=bufC)->bufA ; gemm(bufA,bufC)->bufB
  agg16_kernel<<<agg_blocks, 256, 0, stream>>>(bufC, rowptr, esrc, bufA);
  gemm32_kernel<<<ggrid, 256, 0, stream>>>(bufA, bufC, wt, brel, bufB);
  // l1: agg(bufB)->bufA ; gemm(bufA,bufB)->bufC
  agg16_kernel<<<agg_blocks, 256, 0, stream>>>(bufB, rowptr, esrc, bufA);
  gemm32_kernel<<<ggrid, 256, 0, stream>>>(bufA, bufB, wt + WL, brel + D, bufC);
  // l2: agg(bufC)->bufB ; gemm(bufB,bufC)->bufA
  agg16_kernel<<<agg_blocks, 256, 0, stream>>>(bufC, rowptr, esrc, bufB);
  gemm32_kernel<<<ggrid, 256, 0, stream>>>(bufB, bufC, wt + 2 * WL, brel + 2 * D, bufA);

  pool_head_kernel<<<N_GRAPHS, 256, 0, stream>>>(bufA, batch, W1, b1, W2, b2, out);
}